// Round 18
// baseline (969.690 us; speedup 1.0000x reference)
//
#include <hip/hip_runtime.h>

typedef _Float16 f16;
typedef _Float16 f16x8 __attribute__((ext_vector_type(8)));
typedef float f32x4 __attribute__((ext_vector_type(4)));
typedef float f32x16 __attribute__((ext_vector_type(16)));
typedef uint32_t u32x4 __attribute__((ext_vector_type(4)));

#define NBLK 8
#define NS 2   // independent 32-point streams per wave
#define NIMG 14
#define MFMA32(a, b, c) __builtin_amdgcn_mfma_f32_32x32x16_f16(a, b, c, 0, 0, 0)
#define LOG2E 1.4426950408889634f

// Consumer A-image K-slot -> producer feature index (32x32x16 chaining).
// Producer D: col=lane&31, row=(reg&3)+8*(reg>>2)+4*(lane>>5)  [m74/m101].
// Consumer fragment j = producer regs [8*(j&1), +8) of tile (j>>1).
__device__ __forceinline__ int pinv32(int j, int k) {
  return 32 * (j >> 1) + (k & 3) + 8 * (2 * (j & 1) + ((k >> 2) & 1)) + 4 * (k >> 3);
}
__device__ __forceinline__ float hi_part(float v) { return (float)(f16)v; }  // RNE

__device__ __forceinline__ float fast_exp2(float x) {
  float r; asm("v_exp_f32 %0, %1" : "=v"(r) : "v"(x)); return r;
}
__device__ __forceinline__ float fast_rcp(float x) {
  float r; asm("v_rcp_f32 %0, %1" : "=v"(r) : "v"(x)); return r;
}
__device__ __forceinline__ uint32_t pkrtz_u(float a, float b) {
  auto p = __builtin_amdgcn_cvt_pkrtz(a, b);
  return __builtin_bit_cast(uint32_t, p);
}

// One-time prep for 32x32x16 fragments (identical to R17 — verified).
// Per block i (img 0..13, 512 f16):
//   img 0,1   A1[T]: rows m=32T+(l&31); K slots (k=8*(l>>5)+e):
//     k0-3 = W1 (RNE f16), k4 = b1, k5..15 = 0.
//   img 2..9  A2[T2*4+j]: W2 RNE f16, column pinv32(j,k)
//   img 10..13 A3[j]: W3 RNE f16, rows replicated (row <- row&3), pre-scaled
//     (rows 0,1 x 0.2*log2e; rows 2,3 x 0.1), column pinv32(j,k)
// img 14: couple constants cwp + b2 reordered to C/D reg layout (cwp2).
__global__ void prep_weights(const float* __restrict__ W1, const float* __restrict__ b1,
                             const float* __restrict__ W2, const float* __restrict__ W3,
                             const float* __restrict__ b2, const float* __restrict__ b3,
                             const float* __restrict__ w_perm,
                             const float* __restrict__ g_scale, const float* __restrict__ g_offset,
                             f16* __restrict__ wsp, float* __restrict__ cwp,
                             float* __restrict__ cwp2) {
  int i = blockIdx.x / (NIMG + 1);
  int img = blockIdx.x % (NIMG + 1);
  if (img == NIMG) {
    int tid = threadIdx.x;
    if (tid < 16) {
      int cc = tid & 3;
      float gs = g_scale[i * 4 + cc];
      float sc = 0.2f * log1pf(expf(0.5f * gs));
      cwp[i * 24 + tid] = w_perm[i * 16 + tid] * sc;
    } else if (tid < 20) {
      int r = tid - 16;
      float acc = 0.f;
      for (int cc = 0; cc < 4; ++cc)
        acc += w_perm[i * 16 + r * 4 + cc] * g_offset[i * 4 + cc];
      cwp[i * 24 + 16 + r] = acc;
    } else if (tid < 24) {
      int j = tid - 20;
      float scale = (j < 2) ? (0.2f * LOG2E) : 0.1f;
      cwp[i * 24 + 20 + j] = b3[i * 4 + j] * scale;
    } else if (tid == 24 && i == 0) {
      float acc = 0.f;
      for (int k = 0; k < 32; ++k)
        acc += logf(0.2f * log1pf(expf(0.5f * g_scale[k])));
      cwp[192] = acc;
    }
    {
      int T2 = threadIdx.x >> 5, hi = (threadIdx.x >> 4) & 1, r = threadIdx.x & 15;
      cwp2[i * 64 + threadIdx.x] =
          b2[i * 64 + 32 * T2 + (r & 3) + 8 * (r >> 2) + 4 * hi];
    }
    return;
  }
  int lane = threadIdx.x;
  int row = lane & 31, hi = lane >> 5;
  f16 vals[8];
#pragma unroll
  for (int e = 0; e < 8; ++e) {
    int k = 8 * hi + e;
    float out = 0.f;
    if (img < 2) {
      int m = 32 * img + row;
      if (k < 4)       out = hi_part(W1[i * 256 + m * 4 + k]);
      else if (k == 4) out = hi_part(b1[i * 64 + m]);
      else out = 0.f;
    } else if (img < 10) {
      int q = img - 2, T2 = q >> 2, j = q & 3;
      int m = 32 * T2 + row;
      out = hi_part(W2[i * 4096 + m * 64 + pinv32(j, k)]);
    } else {
      int j = img - 10;
      int rr = row & 3;  // replicate W3 rows -> d3 regs 0..3 = a0..a3 everywhere
      float rs = (rr < 2) ? (0.2f * LOG2E) : 0.1f;
      out = hi_part(W3[i * 256 + rr * 64 + pinv32(j, k)] * rs);
    }
    vals[e] = (f16)out;
  }
  f16x8 vv = {vals[0], vals[1], vals[2], vals[3], vals[4], vals[5], vals[6], vals[7]};
  *(f16x8*)(wsp + ((size_t)i * NIMG + img) * 512 + (size_t)lane * 8) = vv;
}

// 8 consecutive D regs -> packed RTZ f16 + packed relu (8 VALU ops).
template <int OFF>
__device__ __forceinline__ f16x8 cvt_relu(const f32x16 d, uint32_t zero_u) {
  u32x4 u;
  u[0] = pkrtz_u(d[OFF + 0], d[OFF + 1]);
  u[1] = pkrtz_u(d[OFF + 2], d[OFF + 3]);
  u[2] = pkrtz_u(d[OFF + 4], d[OFF + 5]);
  u[3] = pkrtz_u(d[OFF + 6], d[OFF + 7]);
#pragma unroll
  for (int p = 0; p < 4; ++p) {
    uint32_t r;
    asm("v_pk_max_f16 %0, %1, %2" : "=v"(r) : "v"(u[p]), "v"(zero_u));
    u[p] = r;
  }
  return __builtin_bit_cast(f16x8, u);
}

struct Pt {
  float x0, x1, x2, x3, ld;
  uint32_t ch_pk;
};

// Dual-stream 32x32, all-f16 operands. __launch_bounds__(256, 8) forces the
// allocator to <=64 VGPR (the m69 occupancy-bucket boundary: cap doubles
// 4 -> 8 waves/SIMD) — a wave is blocked during its own MFMAs, so only
// co-resident waves can keep the VALU issue port fed.
__global__ __launch_bounds__(256, 8) void cinn_mfma_kernel(
    const float* __restrict__ q_feat, const float* __restrict__ Hc,
    const f16* __restrict__ wf, const float* __restrict__ cwp,
    const float* __restrict__ cwp2,
    float* __restrict__ out_x, float* __restrict__ out_ld, int n) {
  int lane = threadIdx.x & 63;
  int col = lane & 31;
  bool h0 = (lane < 32);
  int wave = (blockIdx.x * blockDim.x + threadIdx.x) >> 6;
  uint32_t zero_u = 0u;
  const uint32_t one_lo_pk = 0x00003C00u;  // packed f16 {1, 0}

  Pt st[NS];
#pragma unroll
  for (int u = 0; u < NS; ++u) {
    int p = wave * (32 * NS) + u * 32 + col;
    if (p >= n) p = n - 1;  // clamped lanes compute identical results (benign)
    float4 xv = *reinterpret_cast<const float4*>(q_feat + (size_t)p * 4);
    st[u].x0 = xv.x; st[u].x1 = xv.y; st[u].x2 = xv.z; st[u].x3 = xv.w;
    st[u].ld = 0.f;
    float2 hv = *reinterpret_cast<const float2*>(Hc + (size_t)p * 2);
    st[u].ch_pk = pkrtz_u(hv.x, hv.y);
  }

  const f32x16 zero16 = {0.f, 0.f, 0.f, 0.f, 0.f, 0.f, 0.f, 0.f,
                         0.f, 0.f, 0.f, 0.f, 0.f, 0.f, 0.f, 0.f};

#pragma unroll 1
  for (int i = 0; i < NBLK; ++i) {
    const f16* wb = wf + (size_t)i * NIMG * 512 + (size_t)lane * 8;
    const float* cw = cwp + i * 24;

    // B1 (k=8*hi+e): hi=0 -> {x0,x1,c0,c1,1,0,0,0}; hi=1 -> 0
    f16x8 B1[NS];
#pragma unroll
    for (int u = 0; u < NS; ++u) {
      uint32_t xh_pk = pkrtz_u(st[u].x0, st[u].x1);
      u32x4 B1u = {h0 ? xh_pk : 0u,
                   h0 ? st[u].ch_pk : 0u,
                   h0 ? one_lo_pk : 0u,
                   0u};
      B1[u] = __builtin_bit_cast(f16x8, B1u);
    }

    // L1: two output tiles (features 0-31, 32-63); A-frags shared
    f16x8 bf[NS][4];
    {
      f16x8 a0 = *(const f16x8*)(wb + 0 * 512);
      f16x8 a1 = *(const f16x8*)(wb + 1 * 512);
#pragma unroll
      for (int u = 0; u < NS; ++u) {
        f32x16 d1a = MFMA32(a0, B1[u], zero16);
        f32x16 d1b = MFMA32(a1, B1[u], zero16);
        bf[u][0] = cvt_relu<0>(d1a, zero_u);
        bf[u][1] = cvt_relu<8>(d1a, zero_u);
        bf[u][2] = cvt_relu<0>(d1b, zero_u);
        bf[u][3] = cvt_relu<8>(d1b, zero_u);
      }
    }

    // L2: per output tile, K=64 via 4 chained MFMAs; streams interleaved so
    // dependent MFMAs are 2 apart; b2 (cwp2) enters as shared C-input.
    f16x8 b3f[NS][4];
#pragma unroll
    for (int T2 = 0; T2 < 2; ++T2) {
      f16x8 ap0 = *(const f16x8*)(wb + (2 + T2 * 4 + 0) * 512);
      f16x8 ap1 = *(const f16x8*)(wb + (2 + T2 * 4 + 1) * 512);
      f16x8 ap2 = *(const f16x8*)(wb + (2 + T2 * 4 + 2) * 512);
      f16x8 ap3 = *(const f16x8*)(wb + (2 + T2 * 4 + 3) * 512);
      const f32x16 cin = *(const f32x16*)(cwp2 + i * 64 + T2 * 32 + (h0 ? 0 : 16));
      f32x16 acc[NS];
#pragma unroll
      for (int u = 0; u < NS; ++u) acc[u] = MFMA32(ap0, bf[u][0], cin);
#pragma unroll
      for (int u = 0; u < NS; ++u) acc[u] = MFMA32(ap1, bf[u][1], acc[u]);
#pragma unroll
      for (int u = 0; u < NS; ++u) acc[u] = MFMA32(ap2, bf[u][2], acc[u]);
#pragma unroll
      for (int u = 0; u < NS; ++u) acc[u] = MFMA32(ap3, bf[u][3], acc[u]);
#pragma unroll
      for (int u = 0; u < NS; ++u) {
        b3f[u][2 * T2 + 0] = cvt_relu<0>(acc[u], zero_u);
        b3f[u][2 * T2 + 1] = cvt_relu<8>(acc[u], zero_u);
      }
    }

    // L3: rows replicated -> regs 0..3 = {2a0*log2e, 2a1*log2e, t2, t3}
    f32x16 d3[NS];
    {
      f16x8 a0 = *(const f16x8*)(wb + 10 * 512);
      f16x8 a1 = *(const f16x8*)(wb + 11 * 512);
      f16x8 a2 = *(const f16x8*)(wb + 12 * 512);
      f16x8 a3 = *(const f16x8*)(wb + 13 * 512);
#pragma unroll
      for (int u = 0; u < NS; ++u) d3[u] = MFMA32(a0, b3f[u][0], zero16);
#pragma unroll
      for (int u = 0; u < NS; ++u) d3[u] = MFMA32(a1, b3f[u][1], d3[u]);
#pragma unroll
      for (int u = 0; u < NS; ++u) d3[u] = MFMA32(a2, b3f[u][2], d3[u]);
#pragma unroll
      for (int u = 0; u < NS; ++u) d3[u] = MFMA32(a3, b3f[u][3], d3[u]);
    }

    // couple (shuffle-free) per stream
#pragma unroll
    for (int u = 0; u < NS; ++u) {
      float a0 = d3[u][0] + cw[20];
      float a1 = d3[u][1] + cw[21];
      float t2 = d3[u][2] + cw[22];
      float t3 = d3[u][3] + cw[23];
      float u0 = fast_exp2(a0), u1 = fast_exp2(a1);      // e^{2a}
      float s0 = fmaf(-4.f, fast_rcp(u0 + 1.f), 2.f);    // 2*tanh(a)
      float s1 = fmaf(-4.f, fast_rcp(u1 + 1.f), 2.f);
      float e0 = fast_exp2(s0 * LOG2E), e1 = fast_exp2(s1 * LOG2E);
      st[u].x2 = fmaf(st[u].x2, e0, t2);
      st[u].x3 = fmaf(st[u].x3, e1, t3);
      st[u].ld += s0 + s1;
      float nx0 = fmaf(st[u].x0, cw[0],  fmaf(st[u].x1, cw[1],  fmaf(st[u].x2, cw[2],  fmaf(st[u].x3, cw[3],  cw[16]))));
      float nx1 = fmaf(st[u].x0, cw[4],  fmaf(st[u].x1, cw[5],  fmaf(st[u].x2, cw[6],  fmaf(st[u].x3, cw[7],  cw[17]))));
      float nx2 = fmaf(st[u].x0, cw[8],  fmaf(st[u].x1, cw[9],  fmaf(st[u].x2, cw[10], fmaf(st[u].x3, cw[11], cw[18]))));
      float nx3 = fmaf(st[u].x0, cw[12], fmaf(st[u].x1, cw[13], fmaf(st[u].x2, cw[14], fmaf(st[u].x3, cw[15], cw[19]))));
      st[u].x0 = nx0; st[u].x1 = nx1; st[u].x2 = nx2; st[u].x3 = nx3;
    }
  }

  if (lane < 32) {
    float lt = cwp[192];
#pragma unroll
    for (int u = 0; u < NS; ++u) {
      int p = wave * (32 * NS) + u * 32 + col;
      if (p >= n) p = n - 1;
      *reinterpret_cast<float4*>(out_x + (size_t)p * 4) =
          make_float4(st[u].x0, st[u].x1, st[u].x2, st[u].x3);
      out_ld[p] = st[u].ld + lt;
    }
  }
}

extern "C" void kernel_launch(void* const* d_in, const int* in_sizes, int n_in,
                              void* d_out, int out_size, void* d_ws, size_t ws_size,
                              hipStream_t stream) {
  const float* q_feat   = (const float*)d_in[0];
  const float* Hc       = (const float*)d_in[1];
  const float* W1       = (const float*)d_in[2];
  const float* b1       = (const float*)d_in[3];
  const float* W2       = (const float*)d_in[4];
  const float* b2       = (const float*)d_in[5];
  const float* W3       = (const float*)d_in[6];
  const float* b3       = (const float*)d_in[7];
  const float* w_perm   = (const float*)d_in[8];
  const float* g_scale  = (const float*)d_in[9];
  const float* g_offset = (const float*)d_in[10];

  int n = in_sizes[0] / 4;
  float* out_x  = (float*)d_out;
  float* out_ld = out_x + (size_t)n * 4;
  f16* wf = (f16*)d_ws;                           // 8*14*512*2 = 114688 B
  float* cwp  = (float*)((char*)d_ws + 114688);   // 193 floats
  float* cwp2 = (float*)((char*)d_ws + 115712);   // 512 floats (b2 reordered)

  hipLaunchKernelGGL(prep_weights, dim3(NBLK * (NIMG + 1)), dim3(64), 0, stream,
                     W1, b1, W2, W3, b2, b3, w_perm, g_scale, g_offset,
                     wf, cwp, cwp2);
  int blocks = (n + 255) / 256;  // 256 points per 256-thread block (64/wave)
  hipLaunchKernelGGL(cinn_mfma_kernel, dim3(blocks), dim3(256), 0, stream,
                     q_feat, Hc, wf, cwp, cwp2, out_x, out_ld, n);
}

// Round 19
// 143.859 us; speedup vs baseline: 6.7406x; 6.7406x over previous
//
#include <hip/hip_runtime.h>

typedef _Float16 f16;
typedef _Float16 f16x8 __attribute__((ext_vector_type(8)));
typedef float f32x4 __attribute__((ext_vector_type(4)));
typedef float f32x16 __attribute__((ext_vector_type(16)));
typedef uint32_t u32x4 __attribute__((ext_vector_type(4)));

#define NBLK 8
#define NS 2   // independent 32-point streams per wave
#define NIMG 14
#define MFMA32(a, b, c) __builtin_amdgcn_mfma_f32_32x32x16_f16(a, b, c, 0, 0, 0)
#define LOG2E 1.4426950408889634f

// Consumer A-image K-slot -> producer feature index (32x32x16 chaining).
// Producer D: col=lane&31, row=(reg&3)+8*(reg>>2)+4*(lane>>5)  [m74/m101].
// Consumer fragment j = producer regs [8*(j&1), +8) of tile (j>>1).
__device__ __forceinline__ int pinv32(int j, int k) {
  return 32 * (j >> 1) + (k & 3) + 8 * (2 * (j & 1) + ((k >> 2) & 1)) + 4 * (k >> 3);
}
__device__ __forceinline__ float hi_part(float v) { return (float)(f16)v; }  // RNE

__device__ __forceinline__ float fast_exp2(float x) {
  float r; asm("v_exp_f32 %0, %1" : "=v"(r) : "v"(x)); return r;
}
__device__ __forceinline__ float fast_rcp(float x) {
  float r; asm("v_rcp_f32 %0, %1" : "=v"(r) : "v"(x)); return r;
}
__device__ __forceinline__ uint32_t pkrtz_u(float a, float b) {
  auto p = __builtin_amdgcn_cvt_pkrtz(a, b);
  return __builtin_bit_cast(uint32_t, p);
}

// One-time prep for 32x32x16 fragments (identical to R17 — verified).
// Per block i (img 0..13, 512 f16):
//   img 0,1   A1[T]: rows m=32T+(l&31); K slots (k=8*(l>>5)+e):
//     k0-3 = W1 (RNE f16), k4 = b1, k5..15 = 0.
//   img 2..9  A2[T2*4+j]: W2 RNE f16, column pinv32(j,k)
//   img 10..13 A3[j]: W3 RNE f16, rows replicated (row <- row&3), pre-scaled
//     (rows 0,1 x 0.2*log2e; rows 2,3 x 0.1), column pinv32(j,k)
// img 14: couple constants cwp + b2 reordered to C/D reg layout (cwp2).
__global__ void prep_weights(const float* __restrict__ W1, const float* __restrict__ b1,
                             const float* __restrict__ W2, const float* __restrict__ W3,
                             const float* __restrict__ b2, const float* __restrict__ b3,
                             const float* __restrict__ w_perm,
                             const float* __restrict__ g_scale, const float* __restrict__ g_offset,
                             f16* __restrict__ wsp, float* __restrict__ cwp,
                             float* __restrict__ cwp2) {
  int i = blockIdx.x / (NIMG + 1);
  int img = blockIdx.x % (NIMG + 1);
  if (img == NIMG) {
    int tid = threadIdx.x;
    if (tid < 16) {
      int cc = tid & 3;
      float gs = g_scale[i * 4 + cc];
      float sc = 0.2f * log1pf(expf(0.5f * gs));
      cwp[i * 24 + tid] = w_perm[i * 16 + tid] * sc;
    } else if (tid < 20) {
      int r = tid - 16;
      float acc = 0.f;
      for (int cc = 0; cc < 4; ++cc)
        acc += w_perm[i * 16 + r * 4 + cc] * g_offset[i * 4 + cc];
      cwp[i * 24 + 16 + r] = acc;
    } else if (tid < 24) {
      int j = tid - 20;
      float scale = (j < 2) ? (0.2f * LOG2E) : 0.1f;
      cwp[i * 24 + 20 + j] = b3[i * 4 + j] * scale;
    } else if (tid == 24 && i == 0) {
      float acc = 0.f;
      for (int k = 0; k < 32; ++k)
        acc += logf(0.2f * log1pf(expf(0.5f * g_scale[k])));
      cwp[192] = acc;
    }
    {
      int T2 = threadIdx.x >> 5, hi = (threadIdx.x >> 4) & 1, r = threadIdx.x & 15;
      cwp2[i * 64 + threadIdx.x] =
          b2[i * 64 + 32 * T2 + (r & 3) + 8 * (r >> 2) + 4 * hi];
    }
    return;
  }
  int lane = threadIdx.x;
  int row = lane & 31, hi = lane >> 5;
  f16 vals[8];
#pragma unroll
  for (int e = 0; e < 8; ++e) {
    int k = 8 * hi + e;
    float out = 0.f;
    if (img < 2) {
      int m = 32 * img + row;
      if (k < 4)       out = hi_part(W1[i * 256 + m * 4 + k]);
      else if (k == 4) out = hi_part(b1[i * 64 + m]);
      else out = 0.f;
    } else if (img < 10) {
      int q = img - 2, T2 = q >> 2, j = q & 3;
      int m = 32 * T2 + row;
      out = hi_part(W2[i * 4096 + m * 64 + pinv32(j, k)]);
    } else {
      int j = img - 10;
      int rr = row & 3;  // replicate W3 rows -> d3 regs 0..3 = a0..a3 everywhere
      float rs = (rr < 2) ? (0.2f * LOG2E) : 0.1f;
      out = hi_part(W3[i * 256 + rr * 64 + pinv32(j, k)] * rs);
    }
    vals[e] = (f16)out;
  }
  f16x8 vv = {vals[0], vals[1], vals[2], vals[3], vals[4], vals[5], vals[6], vals[7]};
  *(f16x8*)(wsp + ((size_t)i * NIMG + img) * 512 + (size_t)lane * 8) = vv;
}

// 8 consecutive D regs -> packed RTZ f16 + packed relu (8 VALU ops).
template <int OFF>
__device__ __forceinline__ f16x8 cvt_relu(const f32x16 d, uint32_t zero_u) {
  u32x4 u;
  u[0] = pkrtz_u(d[OFF + 0], d[OFF + 1]);
  u[1] = pkrtz_u(d[OFF + 2], d[OFF + 3]);
  u[2] = pkrtz_u(d[OFF + 4], d[OFF + 5]);
  u[3] = pkrtz_u(d[OFF + 6], d[OFF + 7]);
#pragma unroll
  for (int p = 0; p < 4; ++p) {
    uint32_t r;
    asm("v_pk_max_f16 %0, %1, %2" : "=v"(r) : "v"(u[p]), "v"(zero_u));
    u[p] = r;
  }
  return __builtin_bit_cast(f16x8, u);
}

struct Pt {
  float x0, x1, x2, x3, ld;
  uint32_t ch_pk;
};

// Dual-stream 32x32 + double-buffered LDS weight staging: the block's 4 waves
// cooperatively global_load_lds the NEXT coupling block's 14 KB of fragment
// images while computing the current one from LDS (ds_read_b128 ~12cyc vs
// L2 ~200-400cyc), sharing the fetch 4-ways. 28 KB LDS — no occupancy impact
// at the 4-blocks/CU VGPR cap. cwp/cwp2 staged once per block.
__global__ __launch_bounds__(256) void cinn_mfma_kernel(
    const float* __restrict__ q_feat, const float* __restrict__ Hc,
    const f16* __restrict__ wf, const float* __restrict__ cwp,
    const float* __restrict__ cwp2,
    float* __restrict__ out_x, float* __restrict__ out_ld, int n) {
  __shared__ __align__(16) f16 sw[2][NIMG * 512];   // 28 KiB
  __shared__ __align__(16) float scw2[512];         // b2 (reordered)
  __shared__ __align__(16) float scw[193];          // couple consts

  int lane = threadIdx.x & 63;
  int wvb = threadIdx.x >> 6;
  int col = lane & 31;
  bool h0 = (lane < 32);
  int wave = (blockIdx.x * blockDim.x + threadIdx.x) >> 6;
  uint32_t zero_u = 0u;
  const uint32_t one_lo_pk = 0x00003C00u;  // packed f16 {1, 0}

  // One-time staging of couple constants.
  for (int idx = threadIdx.x; idx < 193; idx += 256) scw[idx] = cwp[idx];
  for (int idx = threadIdx.x; idx < 512; idx += 256) scw2[idx] = cwp2[idx];
  // Stage coupling block 0 images into buffer 0 (1 KB per instruction).
#pragma unroll
  for (int k = 0; k < 4; ++k) {
    int img = wvb * 4 + k;
    if (img < NIMG) {
      const f16* src = wf + (size_t)img * 512 + (size_t)lane * 8;
      __builtin_amdgcn_global_load_lds((const uint32_t*)src,
                                       (uint32_t*)&sw[0][img * 512], 16, 0, 0);
    }
  }

  Pt st[NS];
#pragma unroll
  for (int u = 0; u < NS; ++u) {
    int p = wave * (32 * NS) + u * 32 + col;
    if (p >= n) p = n - 1;  // clamped lanes compute identical results (benign)
    float4 xv = *reinterpret_cast<const float4*>(q_feat + (size_t)p * 4);
    st[u].x0 = xv.x; st[u].x1 = xv.y; st[u].x2 = xv.z; st[u].x3 = xv.w;
    st[u].ld = 0.f;
    float2 hv = *reinterpret_cast<const float2*>(Hc + (size_t)p * 2);
    st[u].ch_pk = pkrtz_u(hv.x, hv.y);
  }
  __syncthreads();  // staging (incl. global_load_lds vmcnt) complete

  const f32x16 zero16 = {0.f, 0.f, 0.f, 0.f, 0.f, 0.f, 0.f, 0.f,
                         0.f, 0.f, 0.f, 0.f, 0.f, 0.f, 0.f, 0.f};
  int cur = 0;

#pragma unroll 1
  for (int i = 0; i < NBLK; ++i) {
    // Prefetch next coupling block's images (hides under this iter's compute;
    // drained by the end-of-iter barrier).
    if (i < NBLK - 1) {
#pragma unroll
      for (int k = 0; k < 4; ++k) {
        int img = wvb * 4 + k;
        if (img < NIMG) {
          const f16* src = wf + ((size_t)(i + 1) * NIMG + img) * 512 + (size_t)lane * 8;
          __builtin_amdgcn_global_load_lds((const uint32_t*)src,
                                           (uint32_t*)&sw[cur ^ 1][img * 512], 16, 0, 0);
        }
      }
    }

    const f16* wb = &sw[cur][lane * 8];
    const float* cw = scw + i * 24;

    // B1 (k=8*hi+e): hi=0 -> {x0,x1,c0,c1,1,0,0,0}; hi=1 -> 0
    f16x8 B1[NS];
#pragma unroll
    for (int u = 0; u < NS; ++u) {
      uint32_t xh_pk = pkrtz_u(st[u].x0, st[u].x1);
      u32x4 B1u = {h0 ? xh_pk : 0u,
                   h0 ? st[u].ch_pk : 0u,
                   h0 ? one_lo_pk : 0u,
                   0u};
      B1[u] = __builtin_bit_cast(f16x8, B1u);
    }

    // L1: two output tiles (features 0-31, 32-63); A-frags shared
    f16x8 bf[NS][4];
    {
      f16x8 a0 = *(const f16x8*)(wb + 0 * 512);
      f16x8 a1 = *(const f16x8*)(wb + 1 * 512);
#pragma unroll
      for (int u = 0; u < NS; ++u) {
        f32x16 d1a = MFMA32(a0, B1[u], zero16);
        f32x16 d1b = MFMA32(a1, B1[u], zero16);
        bf[u][0] = cvt_relu<0>(d1a, zero_u);
        bf[u][1] = cvt_relu<8>(d1a, zero_u);
        bf[u][2] = cvt_relu<0>(d1b, zero_u);
        bf[u][3] = cvt_relu<8>(d1b, zero_u);
      }
    }

    // L2: per output tile, K=64 via 4 chained MFMAs; streams interleaved so
    // dependent MFMAs are 2 apart; b2 (LDS) enters as shared C-input.
    f16x8 b3f[NS][4];
#pragma unroll
    for (int T2 = 0; T2 < 2; ++T2) {
      f16x8 ap0 = *(const f16x8*)(wb + (2 + T2 * 4 + 0) * 512);
      f16x8 ap1 = *(const f16x8*)(wb + (2 + T2 * 4 + 1) * 512);
      f16x8 ap2 = *(const f16x8*)(wb + (2 + T2 * 4 + 2) * 512);
      f16x8 ap3 = *(const f16x8*)(wb + (2 + T2 * 4 + 3) * 512);
      const f32x16 cin = *(const f32x16*)(scw2 + i * 64 + T2 * 32 + (h0 ? 0 : 16));
      f32x16 acc[NS];
#pragma unroll
      for (int u = 0; u < NS; ++u) acc[u] = MFMA32(ap0, bf[u][0], cin);
#pragma unroll
      for (int u = 0; u < NS; ++u) acc[u] = MFMA32(ap1, bf[u][1], acc[u]);
#pragma unroll
      for (int u = 0; u < NS; ++u) acc[u] = MFMA32(ap2, bf[u][2], acc[u]);
#pragma unroll
      for (int u = 0; u < NS; ++u) acc[u] = MFMA32(ap3, bf[u][3], acc[u]);
#pragma unroll
      for (int u = 0; u < NS; ++u) {
        b3f[u][2 * T2 + 0] = cvt_relu<0>(acc[u], zero_u);
        b3f[u][2 * T2 + 1] = cvt_relu<8>(acc[u], zero_u);
      }
    }

    // L3: rows replicated -> regs 0..3 = {2a0*log2e, 2a1*log2e, t2, t3}
    f32x16 d3[NS];
    {
      f16x8 a0 = *(const f16x8*)(wb + 10 * 512);
      f16x8 a1 = *(const f16x8*)(wb + 11 * 512);
      f16x8 a2 = *(const f16x8*)(wb + 12 * 512);
      f16x8 a3 = *(const f16x8*)(wb + 13 * 512);
#pragma unroll
      for (int u = 0; u < NS; ++u) d3[u] = MFMA32(a0, b3f[u][0], zero16);
#pragma unroll
      for (int u = 0; u < NS; ++u) d3[u] = MFMA32(a1, b3f[u][1], d3[u]);
#pragma unroll
      for (int u = 0; u < NS; ++u) d3[u] = MFMA32(a2, b3f[u][2], d3[u]);
#pragma unroll
      for (int u = 0; u < NS; ++u) d3[u] = MFMA32(a3, b3f[u][3], d3[u]);
    }

    // couple (shuffle-free) per stream
#pragma unroll
    for (int u = 0; u < NS; ++u) {
      float a0 = d3[u][0] + cw[20];
      float a1 = d3[u][1] + cw[21];
      float t2 = d3[u][2] + cw[22];
      float t3 = d3[u][3] + cw[23];
      float u0 = fast_exp2(a0), u1 = fast_exp2(a1);      // e^{2a}
      float s0 = fmaf(-4.f, fast_rcp(u0 + 1.f), 2.f);    // 2*tanh(a)
      float s1 = fmaf(-4.f, fast_rcp(u1 + 1.f), 2.f);
      float e0 = fast_exp2(s0 * LOG2E), e1 = fast_exp2(s1 * LOG2E);
      st[u].x2 = fmaf(st[u].x2, e0, t2);
      st[u].x3 = fmaf(st[u].x3, e1, t3);
      st[u].ld += s0 + s1;
      float nx0 = fmaf(st[u].x0, cw[0],  fmaf(st[u].x1, cw[1],  fmaf(st[u].x2, cw[2],  fmaf(st[u].x3, cw[3],  cw[16]))));
      float nx1 = fmaf(st[u].x0, cw[4],  fmaf(st[u].x1, cw[5],  fmaf(st[u].x2, cw[6],  fmaf(st[u].x3, cw[7],  cw[17]))));
      float nx2 = fmaf(st[u].x0, cw[8],  fmaf(st[u].x1, cw[9],  fmaf(st[u].x2, cw[10], fmaf(st[u].x3, cw[11], cw[18]))));
      float nx3 = fmaf(st[u].x0, cw[12], fmaf(st[u].x1, cw[13], fmaf(st[u].x2, cw[14], fmaf(st[u].x3, cw[15], cw[19]))));
      st[u].x0 = nx0; st[u].x1 = nx1; st[u].x2 = nx2; st[u].x3 = nx3;
    }

    __syncthreads();  // prefetch landed + all reads of sw[cur] done
    cur ^= 1;
  }

  if (lane < 32) {
    float lt = scw[192];
#pragma unroll
    for (int u = 0; u < NS; ++u) {
      int p = wave * (32 * NS) + u * 32 + col;
      if (p >= n) p = n - 1;
      *reinterpret_cast<float4*>(out_x + (size_t)p * 4) =
          make_float4(st[u].x0, st[u].x1, st[u].x2, st[u].x3);
      out_ld[p] = st[u].ld + lt;
    }
  }
}

extern "C" void kernel_launch(void* const* d_in, const int* in_sizes, int n_in,
                              void* d_out, int out_size, void* d_ws, size_t ws_size,
                              hipStream_t stream) {
  const float* q_feat   = (const float*)d_in[0];
  const float* Hc       = (const float*)d_in[1];
  const float* W1       = (const float*)d_in[2];
  const float* b1       = (const float*)d_in[3];
  const float* W2       = (const float*)d_in[4];
  const float* b2       = (const float*)d_in[5];
  const float* W3       = (const float*)d_in[6];
  const float* b3       = (const float*)d_in[7];
  const float* w_perm   = (const float*)d_in[8];
  const float* g_scale  = (const float*)d_in[9];
  const float* g_offset = (const float*)d_in[10];

  int n = in_sizes[0] / 4;
  float* out_x  = (float*)d_out;
  float* out_ld = out_x + (size_t)n * 4;
  f16* wf = (f16*)d_ws;                           // 8*14*512*2 = 114688 B
  float* cwp  = (float*)((char*)d_ws + 114688);   // 193 floats
  float* cwp2 = (float*)((char*)d_ws + 115712);   // 512 floats (b2 reordered)

  hipLaunchKernelGGL(prep_weights, dim3(NBLK * (NIMG + 1)), dim3(64), 0, stream,
                     W1, b1, W2, W3, b2, b3, w_perm, g_scale, g_offset,
                     wf, cwp, cwp2);
  int blocks = (n + 255) / 256;  // 256 points per 256-thread block (64/wave)
  hipLaunchKernelGGL(cinn_mfma_kernel, dim3(blocks), dim3(256), 0, stream,
                     q_feat, Hc, wf, cwp, cwp2, out_x, out_ld, n);
}